// Round 6
// baseline (114.549 us; speedup 1.0000x reference)
//
#include <hip/hip_runtime.h>
#include <math.h>

#define HW 3136
#define WDIM 56
#define HDIM 56
#define DDIM 16
#define CTOT 256
#define TILE_H 14
#define SROWS 16   // TILE_H + 2 halo rows
#define SW 58      // 1 left pad + 56 data + 1 right pad

typedef float v2f __attribute__((ext_vector_type(2)));
typedef float v4f __attribute__((ext_vector_type(4)));

__device__ __forceinline__ float sigmoidf_(float x) {
    return 1.0f / (1.0f + __expf(-x));
}

// packed fp32 fma: c.lo += a.lo*b.lo ; c.hi += a.hi*b.hi  (VOP3P)
__device__ __forceinline__ void pkfma(v2f& c, v2f a, v2f b) {
    asm("v_pk_fma_f32 %0, %1, %2, %0" : "+v"(c) : "v"(a), "v"(b));
}

// K1: spatial means of the two x0 channels per (gb, dd); pre-applies
// cweight/cbias/sigmoid. grid (256,16), block 256. BW-bound (~14us).
__global__ __launch_bounds__(256) void k_means(const float* __restrict__ x,
                                               const float* __restrict__ cw,
                                               const float* __restrict__ cb,
                                               float* __restrict__ scal) {
    const int gb = blockIdx.x;       // bb*64 + g
    const int dd = blockIdx.y;
    const int bb = gb >> 6;
    const int g  = gb & 63;
    const int tid = threadIdx.x;
    __shared__ float red[2][4];

    const float4* p0 = (const float4*)(x + ((((size_t)bb * CTOT + g * 4 + 0) * DDIM + dd) * HW));
    const float4* p1 = (const float4*)(x + ((((size_t)bb * CTOT + g * 4 + 1) * DDIM + dd) * HW));

    float sum0 = 0.f, sum1 = 0.f;
    for (int s = tid; s < HW / 4; s += 256) {
        float4 a = p0[s], b = p1[s];
        sum0 += (a.x + a.y) + (a.z + a.w);
        sum1 += (b.x + b.y) + (b.z + b.w);
    }
    #pragma unroll
    for (int off = 32; off > 0; off >>= 1) {
        sum0 += __shfl_down(sum0, off, 64);
        sum1 += __shfl_down(sum1, off, 64);
    }
    const int wave = tid >> 6, lane = tid & 63;
    if (lane == 0) { red[0][wave] = sum0; red[1][wave] = sum1; }
    __syncthreads();
    if (tid == 0) {
        float m0 = (red[0][0] + red[0][1] + red[0][2] + red[0][3]) * (1.0f / HW);
        float m1 = (red[1][0] + red[1][1] + red[1][2] + red[1][3]) * (1.0f / HW);
        scal[(gb * 2 + 0) * DDIM + dd] = sigmoidf_(cw[0 * DDIM + dd] * m0 + cb[0 * DDIM + dd]);
        scal[(gb * 2 + 1) * DDIM + dd] = sigmoidf_(cw[1 * DDIM + dd] * m1 + cb[1 * DDIM + dd]);
    }
}

// K2: one H-tile / one d-plane per block, 3-plane LDS window (22.5 KB ->
// 7 blocks/CU), quad-per-thread packed conv, cold x0 loads pre-barrier.
// grid (4 th, 16 dd, 256 gb), block 256.
__global__ __launch_bounds__(256, 7) void k_main(const float* __restrict__ x,
                                                 const float* __restrict__ wconv,
                                                 const float* __restrict__ scal,
                                                 float* __restrict__ out) {
    __shared__ __align__(16) v2f ls[3][SROWS][SW];  // {mean, max}
    __shared__ v2f wsh[27];

    const int th  = blockIdx.x;      // 0..3
    const int dd  = blockIdx.y;      // 0..15
    const int gb  = blockIdx.z;      // 0..255
    const int bb  = gb >> 6;
    const int g   = gb & 63;
    const int r0  = th * TILE_H;
    const int tid = threadIdx.x;

    if (tid < 27) wsh[tid] = (v2f){wconv[tid], wconv[27 + tid]};
    // zero the pad columns (staging never writes cols 0 / 57): 3x16x2 = 96
    if (tid < 96) {
        const int row = tid >> 1;
        const int kd = row >> 4, rr = row & 15;
        ls[kd][rr][(tid & 1) ? (SW - 1) : 0] = (v2f){0.f, 0.f};
    }

    const size_t cS = (size_t)DDIM * HW;
    const float* xb = x + ((size_t)bb * CTOT + g * 4) * cS;
    const float* pa = xb + 2 * cS;   // x1 channel 0
    const float* pb = xb + 3 * cS;   // x1 channel 1

    // ---- stage 3 planes x 16 rows x 14 quads = 672 items (2.625/thread) ----
    for (int it = tid; it < 3 * SROWS * 14; it += 256) {
        const int row = it / 14, qd = it - row * 14;
        const int kd = row >> 4, rr = row & 15;
        const int dz = dd + kd - 1;
        const int gr = r0 + rr - 1;
        const int gc0 = 4 * qd;
        v2f m0, m1, m2, m3;
        if (((unsigned)dz < DDIM) & ((unsigned)gr < HDIM)) {
            const size_t o = (size_t)dz * HW + gr * WDIM + gc0;
            const v4f a = *(const v4f*)(pa + o);
            const v4f b = *(const v4f*)(pb + o);
            m0 = (v2f){0.5f * (a[0] + b[0]), fmaxf(a[0], b[0])};
            m1 = (v2f){0.5f * (a[1] + b[1]), fmaxf(a[1], b[1])};
            m2 = (v2f){0.5f * (a[2] + b[2]), fmaxf(a[2], b[2])};
            m3 = (v2f){0.5f * (a[3] + b[3]), fmaxf(a[3], b[3])};
        } else {
            m0 = m1 = m2 = m3 = (v2f){0.f, 0.f};
        }
        v2f* wr = &ls[kd][rr][1 + gc0];
        wr[0] = m0; wr[1] = m1; wr[2] = m2; wr[3] = m3;
    }

    // ---- issue the COLD x0 epilogue loads before the barrier ----
    const int hh = tid / 14;
    const int ww = 4 * (tid - hh * 14);
    const int s  = (r0 + hh) * WDIM + ww;
    const size_t po = (size_t)dd * HW + s;
    v4f v0a, v0b;
    if (tid < TILE_H * 14) {
        v0a = *(const v4f*)(xb + 0 * cS + po);
        v0b = *(const v4f*)(xb + 1 * cS + po);
    }

    __syncthreads();

    if (tid < TILE_H * 14) {         // 196 quad-threads
        v2f acc[4];
        #pragma unroll
        for (int p = 0; p < 4; ++p) acc[p] = (v2f){0.f, 0.f};

        #pragma unroll
        for (int kd = 0; kd < 3; ++kd) {
            #pragma unroll
            for (int kh = 0; kh < 3; ++kh) {
                const v2f* rp = &ls[kd][hh + kh][ww];   // 16B-aligned
                const v4f t0 = *(const v4f*)(rp + 0);
                const v4f t1 = *(const v4f*)(rp + 2);
                const v4f t2 = *(const v4f*)(rp + 4);
                const v2f r[6] = {
                    (v2f){t0[0], t0[1]}, (v2f){t0[2], t0[3]},
                    (v2f){t1[0], t1[1]}, (v2f){t1[2], t1[3]},
                    (v2f){t2[0], t2[1]}, (v2f){t2[2], t2[3]}
                };
                #pragma unroll
                for (int kw = 0; kw < 3; ++kw) {
                    const v2f wv = wsh[kd * 9 + kh * 3 + kw];
                    #pragma unroll
                    for (int p = 0; p < 4; ++p) pkfma(acc[p], r[p + kw], wv);
                }
            }
        }

        // x1 epilogue loads: L2-hot (just staged by this block)
        const v4f v1a = *(const v4f*)(pa + po);
        const v4f v1b = *(const v4f*)(pb + po);

        const float sc0 = scal[(gb * 2 + 0) * DDIM + dd];
        const float sc1 = scal[(gb * 2 + 1) * DDIM + dd];

        int co[4];
        #pragma unroll
        for (int cc = 0; cc < 4; ++cc) {
            const int cs_ = g * 4 + cc;
            co[cc] = 2 * (cs_ & 127) + (cs_ >> 7);
        }

        v4f o0, o1, o2, o3;
        #pragma unroll
        for (int p = 0; p < 4; ++p) {
            const float sig = sigmoidf_(acc[p][0] + acc[p][1]);
            o0[p] = v0a[p] * sc0;
            o1[p] = v0b[p] * sc1;
            o2[p] = v1a[p] * sig;
            o3[p] = v1b[p] * sig;
        }

        float* outb = out + (size_t)bb * CTOT * cS + po;
        *(v4f*)(outb + (size_t)co[0] * cS) = o0;
        *(v4f*)(outb + (size_t)co[1] * cS) = o1;
        *(v4f*)(outb + (size_t)co[2] * cS) = o2;
        *(v4f*)(outb + (size_t)co[3] * cS) = o3;
    }
}

extern "C" void kernel_launch(void* const* d_in, const int* in_sizes, int n_in,
                              void* d_out, int out_size, void* d_ws, size_t ws_size,
                              hipStream_t stream) {
    const float* x     = (const float*)d_in[0];
    const float* cw    = (const float*)d_in[1];
    const float* cb    = (const float*)d_in[2];
    const float* wconv = (const float*)d_in[3];
    float* out  = (float*)d_out;
    float* scal = (float*)d_ws;   // 8192 floats (sigmoided scalars)

    k_means<<<dim3(256, 16), 256, 0, stream>>>(x, cw, cb, scal);
    k_main <<<dim3(4, 16, 256), 256, 0, stream>>>(x, wconv, scal, out);
}

// Round 7
// 94.362 us; speedup vs baseline: 1.2139x; 1.2139x over previous
//
#include <hip/hip_runtime.h>
#include <math.h>

#define HW 3136
#define WDIM 56
#define HDIM 56
#define DDIM 16
#define CTOT 256
#define TILE_H 14
#define SROWS 16   // TILE_H + 2 halo rows
#define SW 58      // 1 left pad + 56 data + 1 right pad

typedef float v2f __attribute__((ext_vector_type(2)));
typedef float v4f __attribute__((ext_vector_type(4)));

__device__ __forceinline__ float sigmoidf_(float x) {
    return 1.0f / (1.0f + __expf(-x));
}

// packed fp32 fma: c.lo += a.lo*b.lo ; c.hi += a.hi*b.hi  (VOP3P)
__device__ __forceinline__ void pkfma(v2f& c, v2f a, v2f b) {
    asm("v_pk_fma_f32 %0, %1, %2, %0" : "+v"(c) : "v"(a), "v"(b));
}

// Heterogeneous single kernel.
//  bid%3==0 -> type A (4096): x0 plane mean->sigmoid->scale->store, regs only.
//  else     -> type B (8192): d-pair 4-plane LDS window conv on x1 (R5 struct).
// Both types at triple-index k work on gb = k>>4 (L2 slab locality).
__global__ __launch_bounds__(256, 5) void k_all(const float* __restrict__ x,
                                                const float* __restrict__ cw,
                                                const float* __restrict__ cb,
                                                const float* __restrict__ wconv,
                                                float* __restrict__ out) {
    __shared__ __align__(16) v2f ls[4][SROWS][SW];  // B: 4 d-window planes {mean,max}
    __shared__ v2f wsh[27];
    __shared__ float reds[2][4];                    // A: cross-wave reduction
    __shared__ float scsh[2];                       // A: sigmoid scalars

    const int bid = blockIdx.x;
    const int tid = threadIdx.x;
    const int trip = bid / 3;
    const int sub  = bid - trip * 3;
    const size_t cS = (size_t)DDIM * HW;

    if (sub == 0) {
        // ================= TYPE A: x0 path =================
        const int gb = trip >> 4;        // 0..255
        const int dd = trip & 15;
        const int bb = gb >> 6, g = gb & 63;

        const float* p0 = x + ((size_t)bb * CTOT + g * 4 + 0) * cS + (size_t)dd * HW;
        const float* p1 = x + ((size_t)bb * CTOT + g * 4 + 1) * cS + (size_t)dd * HW;

        // 784 v4f per channel; thread t holds j = t, t+256, t+512 (+ t+768 if t<16)
        v4f a0 = *(const v4f*)(p0 + 4 * (tid));
        v4f a1 = *(const v4f*)(p0 + 4 * (tid + 256));
        v4f a2 = *(const v4f*)(p0 + 4 * (tid + 512));
        v4f b0 = *(const v4f*)(p1 + 4 * (tid));
        v4f b1 = *(const v4f*)(p1 + 4 * (tid + 256));
        v4f b2 = *(const v4f*)(p1 + 4 * (tid + 512));
        v4f a3 = (v4f){0.f, 0.f, 0.f, 0.f}, b3 = a3;
        if (tid < 16) {
            a3 = *(const v4f*)(p0 + 4 * (tid + 768));
            b3 = *(const v4f*)(p1 + 4 * (tid + 768));
        }

        float s0 = (a0[0]+a0[1]+a0[2]+a0[3]) + (a1[0]+a1[1]+a1[2]+a1[3])
                 + (a2[0]+a2[1]+a2[2]+a2[3]) + (a3[0]+a3[1]+a3[2]+a3[3]);
        float s1 = (b0[0]+b0[1]+b0[2]+b0[3]) + (b1[0]+b1[1]+b1[2]+b1[3])
                 + (b2[0]+b2[1]+b2[2]+b2[3]) + (b3[0]+b3[1]+b3[2]+b3[3]);
        #pragma unroll
        for (int off = 32; off > 0; off >>= 1) {
            s0 += __shfl_down(s0, off, 64);
            s1 += __shfl_down(s1, off, 64);
        }
        const int lane = tid & 63, wave = tid >> 6;
        if (lane == 0) { reds[0][wave] = s0; reds[1][wave] = s1; }
        __syncthreads();
        if (tid == 0) {
            const float m0 = (reds[0][0]+reds[0][1]+reds[0][2]+reds[0][3]) * (1.0f / HW);
            const float m1 = (reds[1][0]+reds[1][1]+reds[1][2]+reds[1][3]) * (1.0f / HW);
            scsh[0] = sigmoidf_(cw[0 * DDIM + dd] * m0 + cb[0 * DDIM + dd]);
            scsh[1] = sigmoidf_(cw[1 * DDIM + dd] * m1 + cb[1 * DDIM + dd]);
        }
        __syncthreads();
        const float sc0 = scsh[0], sc1 = scsh[1];

        // shuffled output channels for cc=0,1
        const int cs0 = g * 4 + 0, cs1 = g * 4 + 1;
        const int co0 = 2 * (cs0 & 127) + (cs0 >> 7);
        const int co1 = 2 * (cs1 & 127) + (cs1 >> 7);
        float* o0 = out + ((size_t)bb * CTOT + co0) * cS + (size_t)dd * HW;
        float* o1 = out + ((size_t)bb * CTOT + co1) * cS + (size_t)dd * HW;

        #pragma unroll
        for (int p = 0; p < 4; ++p) { a0[p] *= sc0; a1[p] *= sc0; a2[p] *= sc0; a3[p] *= sc0;
                                      b0[p] *= sc1; b1[p] *= sc1; b2[p] *= sc1; b3[p] *= sc1; }
        *(v4f*)(o0 + 4 * (tid))       = a0;
        *(v4f*)(o0 + 4 * (tid + 256)) = a1;
        *(v4f*)(o0 + 4 * (tid + 512)) = a2;
        *(v4f*)(o1 + 4 * (tid))       = b0;
        *(v4f*)(o1 + 4 * (tid + 256)) = b1;
        *(v4f*)(o1 + 4 * (tid + 512)) = b2;
        if (tid < 16) {
            *(v4f*)(o0 + 4 * (tid + 768)) = a3;
            *(v4f*)(o1 + 4 * (tid + 768)) = b3;
        }
        return;
    }

    // ================= TYPE B: x1 conv path =================
    const int i   = trip * 2 + (sub - 1);   // 0..8191
    const int th  = i & 3;
    const int ddp = (i >> 2) & 7;
    const int gb  = i >> 5;
    const int bb  = gb >> 6;
    const int g   = gb & 63;
    const int dd0 = 2 * ddp;
    const int r0  = th * TILE_H;

    if (tid < 27) wsh[tid] = (v2f){wconv[tid], wconv[27 + tid]};
    // zero the pad columns (staging never writes cols 0 / 57)
    if (tid < 128) {
        const int wp = tid >> 5, rr = (tid >> 1) & 15;
        ls[wp][rr][(tid & 1) ? (SW - 1) : 0] = (v2f){0.f, 0.f};
    }

    const float* xb = x + ((size_t)bb * CTOT + g * 4) * cS;
    const float* pa = xb + 2 * cS;   // x1 channel 0
    const float* pb = xb + 3 * cS;   // x1 channel 1

    // stage 4 planes x 16 rows x 14 quads = 896 items
    for (int it = tid; it < 4 * SROWS * 14; it += 256) {
        const int row = it / 14, qd = it - row * 14;
        const int wp = row >> 4, rr = row & 15;
        const int dz = dd0 + wp - 1;
        const int gr = r0 + rr - 1;
        const int gc0 = 4 * qd;
        v2f m0, m1, m2, m3;
        if (((unsigned)dz < DDIM) & ((unsigned)gr < HDIM)) {
            const size_t o = (size_t)dz * HW + gr * WDIM + gc0;
            const v4f a = *(const v4f*)(pa + o);
            const v4f b = *(const v4f*)(pb + o);
            m0 = (v2f){0.5f * (a[0] + b[0]), fmaxf(a[0], b[0])};
            m1 = (v2f){0.5f * (a[1] + b[1]), fmaxf(a[1], b[1])};
            m2 = (v2f){0.5f * (a[2] + b[2]), fmaxf(a[2], b[2])};
            m3 = (v2f){0.5f * (a[3] + b[3]), fmaxf(a[3], b[3])};
        } else {
            m0 = m1 = m2 = m3 = (v2f){0.f, 0.f};
        }
        v2f* wr = &ls[wp][rr][1 + gc0];
        wr[0] = m0; wr[1] = m1; wr[2] = m2; wr[3] = m3;
    }
    __syncthreads();

    if (tid < TILE_H * 14) {         // 196 quad-threads, both planes
        const int hh = tid / 14;
        const int ww = 4 * (tid - hh * 14);

        v2f acc0[4], acc1[4];
        #pragma unroll
        for (int p = 0; p < 4; ++p) { acc0[p] = (v2f){0.f, 0.f}; acc1[p] = (v2f){0.f, 0.f}; }

        #pragma unroll
        for (int wp = 0; wp < 4; ++wp) {
            #pragma unroll
            for (int kh = 0; kh < 3; ++kh) {
                const v2f* rp = &ls[wp][hh + kh][ww];   // 16B-aligned
                const v4f t0 = *(const v4f*)(rp + 0);
                const v4f t1 = *(const v4f*)(rp + 2);
                const v4f t2 = *(const v4f*)(rp + 4);
                const v2f r[6] = {
                    (v2f){t0[0], t0[1]}, (v2f){t0[2], t0[3]},
                    (v2f){t1[0], t1[1]}, (v2f){t1[2], t1[3]},
                    (v2f){t2[0], t2[1]}, (v2f){t2[2], t2[3]}
                };
                if (wp < 3) {
                    #pragma unroll
                    for (int kw = 0; kw < 3; ++kw) {
                        const v2f wv = wsh[wp * 9 + kh * 3 + kw];
                        #pragma unroll
                        for (int p = 0; p < 4; ++p) pkfma(acc0[p], r[p + kw], wv);
                    }
                }
                if (wp >= 1) {
                    #pragma unroll
                    for (int kw = 0; kw < 3; ++kw) {
                        const v2f wv = wsh[(wp - 1) * 9 + kh * 3 + kw];
                        #pragma unroll
                        for (int p = 0; p < 4; ++p) pkfma(acc1[p], r[p + kw], wv);
                    }
                }
            }
        }

        const int cs2 = g * 4 + 2, cs3 = g * 4 + 3;
        const int co2 = 2 * (cs2 & 127) + (cs2 >> 7);
        const int co3 = 2 * (cs3 & 127) + (cs3 >> 7);

        const int s = (r0 + hh) * WDIM + ww;   // 16B-aligned
        float* outb = out + (size_t)bb * CTOT * cS + s;
        #pragma unroll
        for (int pl = 0; pl < 2; ++pl) {
            const v2f* acc = pl ? acc1 : acc0;
            const size_t po = (size_t)(dd0 + pl) * HW;
            const v4f v1a = *(const v4f*)(pa + po + s);   // L2-hot (just staged)
            const v4f v1b = *(const v4f*)(pb + po + s);
            v4f o2, o3;
            #pragma unroll
            for (int p = 0; p < 4; ++p) {
                const float sig = sigmoidf_(acc[p][0] + acc[p][1]);
                o2[p] = v1a[p] * sig;
                o3[p] = v1b[p] * sig;
            }
            *(v4f*)(outb + (size_t)co2 * cS + po) = o2;
            *(v4f*)(outb + (size_t)co3 * cS + po) = o3;
        }
    }
}

extern "C" void kernel_launch(void* const* d_in, const int* in_sizes, int n_in,
                              void* d_out, int out_size, void* d_ws, size_t ws_size,
                              hipStream_t stream) {
    const float* x     = (const float*)d_in[0];
    const float* cw    = (const float*)d_in[1];
    const float* cb    = (const float*)d_in[2];
    const float* wconv = (const float*)d_in[3];
    float* out = (float*)d_out;

    k_all<<<dim3(12288), 256, 0, stream>>>(x, cw, cb, wconv, out);
}

// Round 9
// 88.396 us; speedup vs baseline: 1.2959x; 1.0675x over previous
//
#include <hip/hip_runtime.h>
#include <math.h>

#define HW 3136
#define WDIM 56
#define HDIM 56
#define DDIM 16
#define CTOT 256
#define TILE_H 14
#define SROWS 16   // TILE_H + 2 halo rows
#define SW 60      // [pad0][data 1..56][pad57][unused 58,59] ; 240B row, 16B-aligned

typedef float v4f __attribute__((ext_vector_type(4)));
typedef unsigned int u32;
typedef u32 u32x2 __attribute__((ext_vector_type(2)));
typedef u32 u32x4 __attribute__((ext_vector_type(4)));
typedef __fp16 h2 __attribute__((ext_vector_type(2)));

__device__ __forceinline__ float sigmoidf_(float x) {
    return 1.0f / (1.0f + __expf(-x));
}

// pack {lo,hi} f32 -> f16x2 in a u32 (v_cvt_pkrtz_f16_f32)
__device__ __forceinline__ u32 packh2(float lo, float hi) {
    h2 r = __builtin_amdgcn_cvt_pkrtz(lo, hi);
    union { h2 h; u32 u; } c; c.h = r; return c.u;
}
__device__ __forceinline__ h2 ash2(u32 u) {
    union { u32 u; h2 h; } c; c.u = u; return c.h;
}

// Heterogeneous single kernel.
//  bid%3==0 -> type A (4096): x0 plane mean->sigmoid->scale->store, regs only.
//  else     -> type B (8192): d-pair 4-plane LDS window conv on x1, f16x2+fdot2.
__global__ __launch_bounds__(256, 8) void k_all(const float* __restrict__ x,
                                                const float* __restrict__ cw,
                                                const float* __restrict__ cb,
                                                const float* __restrict__ wconv,
                                                float* __restrict__ out) {
    __shared__ __align__(16) u32 ls[4][SROWS][SW];  // B: f16x2 {mean,max}
    __shared__ u32 wsh[27];                         // f16x2 {w_mean, w_max}
    __shared__ float reds[2][4];                    // A: cross-wave reduction
    __shared__ float scsh[2];                       // A: sigmoid scalars

    const int bid = blockIdx.x;
    const int tid = threadIdx.x;
    const int trip = bid / 3;
    const int sub  = bid - trip * 3;
    const size_t cS = (size_t)DDIM * HW;

    if (sub == 0) {
        // ================= TYPE A: x0 path =================
        const int gb = trip >> 4;        // 0..255
        const int dd = trip & 15;
        const int bb = gb >> 6, g = gb & 63;

        const float* p0 = x + ((size_t)bb * CTOT + g * 4 + 0) * cS + (size_t)dd * HW;
        const float* p1 = x + ((size_t)bb * CTOT + g * 4 + 1) * cS + (size_t)dd * HW;

        v4f a0 = __builtin_nontemporal_load((const v4f*)(p0 + 4 * (tid)));
        v4f a1 = __builtin_nontemporal_load((const v4f*)(p0 + 4 * (tid + 256)));
        v4f a2 = __builtin_nontemporal_load((const v4f*)(p0 + 4 * (tid + 512)));
        v4f b0 = __builtin_nontemporal_load((const v4f*)(p1 + 4 * (tid)));
        v4f b1 = __builtin_nontemporal_load((const v4f*)(p1 + 4 * (tid + 256)));
        v4f b2 = __builtin_nontemporal_load((const v4f*)(p1 + 4 * (tid + 512)));
        v4f a3 = (v4f){0.f, 0.f, 0.f, 0.f}, b3 = a3;
        if (tid < 16) {
            a3 = __builtin_nontemporal_load((const v4f*)(p0 + 4 * (tid + 768)));
            b3 = __builtin_nontemporal_load((const v4f*)(p1 + 4 * (tid + 768)));
        }

        float s0 = (a0[0]+a0[1]+a0[2]+a0[3]) + (a1[0]+a1[1]+a1[2]+a1[3])
                 + (a2[0]+a2[1]+a2[2]+a2[3]) + (a3[0]+a3[1]+a3[2]+a3[3]);
        float s1 = (b0[0]+b0[1]+b0[2]+b0[3]) + (b1[0]+b1[1]+b1[2]+b1[3])
                 + (b2[0]+b2[1]+b2[2]+b2[3]) + (b3[0]+b3[1]+b3[2]+b3[3]);
        #pragma unroll
        for (int off = 32; off > 0; off >>= 1) {
            s0 += __shfl_down(s0, off, 64);
            s1 += __shfl_down(s1, off, 64);
        }
        const int lane = tid & 63, wave = tid >> 6;
        if (lane == 0) { reds[0][wave] = s0; reds[1][wave] = s1; }
        __syncthreads();
        if (tid == 0) {
            const float m0 = (reds[0][0]+reds[0][1]+reds[0][2]+reds[0][3]) * (1.0f / HW);
            const float m1 = (reds[1][0]+reds[1][1]+reds[1][2]+reds[1][3]) * (1.0f / HW);
            scsh[0] = sigmoidf_(cw[0 * DDIM + dd] * m0 + cb[0 * DDIM + dd]);
            scsh[1] = sigmoidf_(cw[1 * DDIM + dd] * m1 + cb[1 * DDIM + dd]);
        }
        __syncthreads();
        const float sc0 = scsh[0], sc1 = scsh[1];

        const int cs0 = g * 4 + 0, cs1 = g * 4 + 1;
        const int co0 = 2 * (cs0 & 127) + (cs0 >> 7);
        const int co1 = 2 * (cs1 & 127) + (cs1 >> 7);
        float* o0 = out + ((size_t)bb * CTOT + co0) * cS + (size_t)dd * HW;
        float* o1 = out + ((size_t)bb * CTOT + co1) * cS + (size_t)dd * HW;

        #pragma unroll
        for (int p = 0; p < 4; ++p) { a0[p] *= sc0; a1[p] *= sc0; a2[p] *= sc0; a3[p] *= sc0;
                                      b0[p] *= sc1; b1[p] *= sc1; b2[p] *= sc1; b3[p] *= sc1; }
        __builtin_nontemporal_store(a0, (v4f*)(o0 + 4 * (tid)));
        __builtin_nontemporal_store(a1, (v4f*)(o0 + 4 * (tid + 256)));
        __builtin_nontemporal_store(a2, (v4f*)(o0 + 4 * (tid + 512)));
        __builtin_nontemporal_store(b0, (v4f*)(o1 + 4 * (tid)));
        __builtin_nontemporal_store(b1, (v4f*)(o1 + 4 * (tid + 256)));
        __builtin_nontemporal_store(b2, (v4f*)(o1 + 4 * (tid + 512)));
        if (tid < 16) {
            __builtin_nontemporal_store(a3, (v4f*)(o0 + 4 * (tid + 768)));
            __builtin_nontemporal_store(b3, (v4f*)(o1 + 4 * (tid + 768)));
        }
        return;
    }

    // ================= TYPE B: x1 conv path =================
    const int i   = trip * 2 + (sub - 1);   // 0..8191
    const int th  = i & 3;
    const int ddp = (i >> 2) & 7;
    const int gb  = i >> 5;
    const int bb  = gb >> 6;
    const int g   = gb & 63;
    const int dd0 = 2 * ddp;
    const int r0  = th * TILE_H;

    if (tid < 27) wsh[tid] = packh2(wconv[tid], wconv[27 + tid]);
    // zero pad columns 0 and 57 (4 planes x 16 rows x 2) = 128
    if (tid < 128) {
        const int wp = tid >> 5, rr = (tid >> 1) & 15;
        ls[wp][rr][(tid & 1) ? 57 : 0] = 0u;
    }

    const float* xb = x + ((size_t)bb * CTOT + g * 4) * cS;
    const float* pa = xb + 2 * cS;   // x1 channel 0
    const float* pb = xb + 3 * cS;   // x1 channel 1

    // stage 4 planes x 16 rows x 14 quads = 896 items
    for (int it = tid; it < 4 * SROWS * 14; it += 256) {
        const int row = it / 14, qd = it - row * 14;
        const int wp = row >> 4, rr = row & 15;
        const int dz = dd0 + wp - 1;
        const int gr = r0 + rr - 1;
        const int gc0 = 4 * qd;
        u32 m0, m1, m2, m3;
        if (((unsigned)dz < DDIM) & ((unsigned)gr < HDIM)) {
            const size_t o = (size_t)dz * HW + gr * WDIM + gc0;
            const v4f a = *(const v4f*)(pa + o);
            const v4f b = *(const v4f*)(pb + o);
            m0 = packh2(0.5f * (a[0] + b[0]), fmaxf(a[0], b[0]));
            m1 = packh2(0.5f * (a[1] + b[1]), fmaxf(a[1], b[1]));
            m2 = packh2(0.5f * (a[2] + b[2]), fmaxf(a[2], b[2]));
            m3 = packh2(0.5f * (a[3] + b[3]), fmaxf(a[3], b[3]));
        } else {
            m0 = m1 = m2 = m3 = 0u;
        }
        u32* wr = &ls[wp][rr][1 + gc0];
        wr[0] = m0; wr[1] = m1; wr[2] = m2; wr[3] = m3;
    }
    __syncthreads();

    if (tid < TILE_H * 14) {         // 196 quad-threads, both planes
        const int hh = tid / 14;
        const int ww = 4 * (tid - hh * 14);

        float acc0[4] = {0.f, 0.f, 0.f, 0.f};
        float acc1[4] = {0.f, 0.f, 0.f, 0.f};

        #pragma unroll
        for (int wp = 0; wp < 4; ++wp) {
            #pragma unroll
            for (int kh = 0; kh < 3; ++kh) {
                const u32* rp = &ls[wp][hh + kh][ww];      // 16B-aligned
                const u32x4 q  = *(const u32x4*)rp;        // padded idx ww..ww+3
                const u32x2 q2 = *(const u32x2*)(rp + 4);  // ww+4, ww+5
                const u32 vv[6] = {q[0], q[1], q[2], q[3], q2[0], q2[1]};
                if (wp < 3) {
                    #pragma unroll
                    for (int kw = 0; kw < 3; ++kw) {
                        const h2 wv = ash2(wsh[wp * 9 + kh * 3 + kw]);
                        #pragma unroll
                        for (int p = 0; p < 4; ++p)
                            acc0[p] = __builtin_amdgcn_fdot2(ash2(vv[p + kw]), wv, acc0[p], false);
                    }
                }
                if (wp >= 1) {
                    #pragma unroll
                    for (int kw = 0; kw < 3; ++kw) {
                        const h2 wv = ash2(wsh[(wp - 1) * 9 + kh * 3 + kw]);
                        #pragma unroll
                        for (int p = 0; p < 4; ++p)
                            acc1[p] = __builtin_amdgcn_fdot2(ash2(vv[p + kw]), wv, acc1[p], false);
                    }
                }
            }
        }

        const int cs2 = g * 4 + 2, cs3 = g * 4 + 3;
        const int co2 = 2 * (cs2 & 127) + (cs2 >> 7);
        const int co3 = 2 * (cs3 & 127) + (cs3 >> 7);

        const int s = (r0 + hh) * WDIM + ww;   // 16B-aligned
        float* outb = out + (size_t)bb * CTOT * cS + s;
        #pragma unroll
        for (int pl = 0; pl < 2; ++pl) {
            const float* acc = pl ? acc1 : acc0;
            const size_t po = (size_t)(dd0 + pl) * HW;
            const v4f v1a = *(const v4f*)(pa + po + s);   // L2-hot (just staged)
            const v4f v1b = *(const v4f*)(pb + po + s);
            v4f o2, o3;
            #pragma unroll
            for (int p = 0; p < 4; ++p) {
                const float sig = sigmoidf_(acc[p]);
                o2[p] = v1a[p] * sig;
                o3[p] = v1b[p] * sig;
            }
            __builtin_nontemporal_store(o2, (v4f*)(outb + (size_t)co2 * cS + po));
            __builtin_nontemporal_store(o3, (v4f*)(outb + (size_t)co3 * cS + po));
        }
    }
}

extern "C" void kernel_launch(void* const* d_in, const int* in_sizes, int n_in,
                              void* d_out, int out_size, void* d_ws, size_t ws_size,
                              hipStream_t stream) {
    const float* x     = (const float*)d_in[0];
    const float* cw    = (const float*)d_in[1];
    const float* cb    = (const float*)d_in[2];
    const float* wconv = (const float*)d_in[3];
    float* out = (float*)d_out;

    k_all<<<dim3(12288), 256, 0, stream>>>(x, cw, cb, wconv, out);
}

// Round 10
// 71.640 us; speedup vs baseline: 1.5989x; 1.2339x over previous
//
#include <hip/hip_runtime.h>
#include <math.h>

#define HW 3136
#define WDIM 56
#define HDIM 56
#define DDIM 16
#define CTOT 256
#define TILE_H 14
#define SROWS 16   // TILE_H + 2 halo rows
#define SW 60      // [pad0][data 1..56][pad57][unused 58,59] ; 240B row, 16B-aligned

typedef float v4f __attribute__((ext_vector_type(4)));
typedef unsigned int u32;
typedef u32 u32x2 __attribute__((ext_vector_type(2)));
typedef u32 u32x4 __attribute__((ext_vector_type(4)));
typedef __fp16 h2 __attribute__((ext_vector_type(2)));

__device__ __forceinline__ float sigmoidf_(float x) {
    return 1.0f / (1.0f + __expf(-x));
}

// pack {lo,hi} f32 -> f16x2 in a u32 (v_cvt_pkrtz_f16_f32)
__device__ __forceinline__ u32 packh2(float lo, float hi) {
    h2 r = __builtin_amdgcn_cvt_pkrtz(lo, hi);
    union { h2 h; u32 u; } c; c.h = r; return c.u;
}
__device__ __forceinline__ h2 ash2(u32 u) {
    union { u32 u; h2 h; } c; c.u = u; return c.h;
}

// Heterogeneous single kernel with XCD-slab swizzle:
//  xcd = bid&7, li = bid>>3, gb = (li/48)*8 + xcd, r = li%48.
//  All 48 blocks (16 type A + 32 type B) of one gb-slab land on one XCD,
//  adjacent in dispatch order -> slab (3.2 MB) stays L2-resident.
//  r<16  -> type A: x0 plane mean->sigmoid->scale->store, regs only (dd=r).
//  r>=16 -> type B: d-pair 4-plane LDS window conv on x1, f16x2+fdot2.
__global__ __launch_bounds__(256, 8) void k_all(const float* __restrict__ x,
                                                const float* __restrict__ cw,
                                                const float* __restrict__ cb,
                                                const float* __restrict__ wconv,
                                                float* __restrict__ out) {
    __shared__ __align__(16) u32 ls[4][SROWS][SW];  // B: f16x2 {mean,max}
    __shared__ u32 wsh[27];                         // f16x2 {w_mean, w_max}
    __shared__ float reds[2][4];                    // A: cross-wave reduction
    __shared__ float scsh[2];                       // A: sigmoid scalars

    const int bid = blockIdx.x;
    const int tid = threadIdx.x;
    const int xcd = bid & 7;
    const int li  = bid >> 3;            // 0..1535
    const int gb  = ((li / 48) << 3) + xcd;   // 0..255
    const int r   = li % 48;
    const int bb  = gb >> 6, g = gb & 63;
    const size_t cS = (size_t)DDIM * HW;

    if (r < 16) {
        // ================= TYPE A: x0 path =================
        const int dd = r;

        const float* p0 = x + ((size_t)bb * CTOT + g * 4 + 0) * cS + (size_t)dd * HW;
        const float* p1 = x + ((size_t)bb * CTOT + g * 4 + 1) * cS + (size_t)dd * HW;

        v4f a0 = __builtin_nontemporal_load((const v4f*)(p0 + 4 * (tid)));
        v4f a1 = __builtin_nontemporal_load((const v4f*)(p0 + 4 * (tid + 256)));
        v4f a2 = __builtin_nontemporal_load((const v4f*)(p0 + 4 * (tid + 512)));
        v4f b0 = __builtin_nontemporal_load((const v4f*)(p1 + 4 * (tid)));
        v4f b1 = __builtin_nontemporal_load((const v4f*)(p1 + 4 * (tid + 256)));
        v4f b2 = __builtin_nontemporal_load((const v4f*)(p1 + 4 * (tid + 512)));
        v4f a3 = (v4f){0.f, 0.f, 0.f, 0.f}, b3 = a3;
        if (tid < 16) {
            a3 = __builtin_nontemporal_load((const v4f*)(p0 + 4 * (tid + 768)));
            b3 = __builtin_nontemporal_load((const v4f*)(p1 + 4 * (tid + 768)));
        }

        float s0 = (a0[0]+a0[1]+a0[2]+a0[3]) + (a1[0]+a1[1]+a1[2]+a1[3])
                 + (a2[0]+a2[1]+a2[2]+a2[3]) + (a3[0]+a3[1]+a3[2]+a3[3]);
        float s1 = (b0[0]+b0[1]+b0[2]+b0[3]) + (b1[0]+b1[1]+b1[2]+b1[3])
                 + (b2[0]+b2[1]+b2[2]+b2[3]) + (b3[0]+b3[1]+b3[2]+b3[3]);
        #pragma unroll
        for (int off = 32; off > 0; off >>= 1) {
            s0 += __shfl_down(s0, off, 64);
            s1 += __shfl_down(s1, off, 64);
        }
        const int lane = tid & 63, wave = tid >> 6;
        if (lane == 0) { reds[0][wave] = s0; reds[1][wave] = s1; }
        __syncthreads();
        if (tid == 0) {
            const float m0 = (reds[0][0]+reds[0][1]+reds[0][2]+reds[0][3]) * (1.0f / HW);
            const float m1 = (reds[1][0]+reds[1][1]+reds[1][2]+reds[1][3]) * (1.0f / HW);
            scsh[0] = sigmoidf_(cw[0 * DDIM + dd] * m0 + cb[0 * DDIM + dd]);
            scsh[1] = sigmoidf_(cw[1 * DDIM + dd] * m1 + cb[1 * DDIM + dd]);
        }
        __syncthreads();
        const float sc0 = scsh[0], sc1 = scsh[1];

        const int cs0 = g * 4 + 0, cs1 = g * 4 + 1;
        const int co0 = 2 * (cs0 & 127) + (cs0 >> 7);
        const int co1 = 2 * (cs1 & 127) + (cs1 >> 7);
        float* o0 = out + ((size_t)bb * CTOT + co0) * cS + (size_t)dd * HW;
        float* o1 = out + ((size_t)bb * CTOT + co1) * cS + (size_t)dd * HW;

        #pragma unroll
        for (int p = 0; p < 4; ++p) { a0[p] *= sc0; a1[p] *= sc0; a2[p] *= sc0; a3[p] *= sc0;
                                      b0[p] *= sc1; b1[p] *= sc1; b2[p] *= sc1; b3[p] *= sc1; }
        __builtin_nontemporal_store(a0, (v4f*)(o0 + 4 * (tid)));
        __builtin_nontemporal_store(a1, (v4f*)(o0 + 4 * (tid + 256)));
        __builtin_nontemporal_store(a2, (v4f*)(o0 + 4 * (tid + 512)));
        __builtin_nontemporal_store(b0, (v4f*)(o1 + 4 * (tid)));
        __builtin_nontemporal_store(b1, (v4f*)(o1 + 4 * (tid + 256)));
        __builtin_nontemporal_store(b2, (v4f*)(o1 + 4 * (tid + 512)));
        if (tid < 16) {
            __builtin_nontemporal_store(a3, (v4f*)(o0 + 4 * (tid + 768)));
            __builtin_nontemporal_store(b3, (v4f*)(o1 + 4 * (tid + 768)));
        }
        return;
    }

    // ================= TYPE B: x1 conv path =================
    const int j   = r - 16;          // 0..31
    const int th  = j & 3;
    const int ddp = j >> 2;          // 0..7
    const int dd0 = 2 * ddp;
    const int r0  = th * TILE_H;

    if (tid < 27) wsh[tid] = packh2(wconv[tid], wconv[27 + tid]);
    // zero pad columns 0 and 57 (4 planes x 16 rows x 2) = 128
    if (tid < 128) {
        const int wp = tid >> 5, rr = (tid >> 1) & 15;
        ls[wp][rr][(tid & 1) ? 57 : 0] = 0u;
    }

    const float* xb = x + ((size_t)bb * CTOT + g * 4) * cS;
    const float* pa = xb + 2 * cS;   // x1 channel 0
    const float* pb = xb + 3 * cS;   // x1 channel 1

    // stage 4 planes x 16 rows x 14 quads = 896 items
    for (int it = tid; it < 4 * SROWS * 14; it += 256) {
        const int row = it / 14, qd = it - row * 14;
        const int wp = row >> 4, rr = row & 15;
        const int dz = dd0 + wp - 1;
        const int gr = r0 + rr - 1;
        const int gc0 = 4 * qd;
        u32 m0, m1, m2, m3;
        if (((unsigned)dz < DDIM) & ((unsigned)gr < HDIM)) {
            const size_t o = (size_t)dz * HW + gr * WDIM + gc0;
            const v4f a = *(const v4f*)(pa + o);
            const v4f b = *(const v4f*)(pb + o);
            m0 = packh2(0.5f * (a[0] + b[0]), fmaxf(a[0], b[0]));
            m1 = packh2(0.5f * (a[1] + b[1]), fmaxf(a[1], b[1]));
            m2 = packh2(0.5f * (a[2] + b[2]), fmaxf(a[2], b[2]));
            m3 = packh2(0.5f * (a[3] + b[3]), fmaxf(a[3], b[3]));
        } else {
            m0 = m1 = m2 = m3 = 0u;
        }
        u32* wr = &ls[wp][rr][1 + gc0];
        wr[0] = m0; wr[1] = m1; wr[2] = m2; wr[3] = m3;
    }
    __syncthreads();

    if (tid < TILE_H * 14) {         // 196 quad-threads, both planes
        const int hh = tid / 14;
        const int ww = 4 * (tid - hh * 14);

        float acc0[4] = {0.f, 0.f, 0.f, 0.f};
        float acc1[4] = {0.f, 0.f, 0.f, 0.f};

        #pragma unroll
        for (int wp = 0; wp < 4; ++wp) {
            #pragma unroll
            for (int kh = 0; kh < 3; ++kh) {
                const u32* rp = &ls[wp][hh + kh][ww];      // 16B-aligned
                const u32x4 q  = *(const u32x4*)rp;        // padded idx ww..ww+3
                const u32x2 q2 = *(const u32x2*)(rp + 4);  // ww+4, ww+5
                const u32 vv[6] = {q[0], q[1], q[2], q[3], q2[0], q2[1]};
                if (wp < 3) {
                    #pragma unroll
                    for (int kw = 0; kw < 3; ++kw) {
                        const h2 wv = ash2(wsh[wp * 9 + kh * 3 + kw]);
                        #pragma unroll
                        for (int p = 0; p < 4; ++p)
                            acc0[p] = __builtin_amdgcn_fdot2(ash2(vv[p + kw]), wv, acc0[p], false);
                    }
                }
                if (wp >= 1) {
                    #pragma unroll
                    for (int kw = 0; kw < 3; ++kw) {
                        const h2 wv = ash2(wsh[(wp - 1) * 9 + kh * 3 + kw]);
                        #pragma unroll
                        for (int p = 0; p < 4; ++p)
                            acc1[p] = __builtin_amdgcn_fdot2(ash2(vv[p + kw]), wv, acc1[p], false);
                    }
                }
            }
        }

        const int cs2 = g * 4 + 2, cs3 = g * 4 + 3;
        const int co2 = 2 * (cs2 & 127) + (cs2 >> 7);
        const int co3 = 2 * (cs3 & 127) + (cs3 >> 7);

        const int s = (r0 + hh) * WDIM + ww;   // 16B-aligned
        float* outb = out + (size_t)bb * CTOT * cS + s;
        #pragma unroll
        for (int pl = 0; pl < 2; ++pl) {
            const float* acc = pl ? acc1 : acc0;
            const size_t po = (size_t)(dd0 + pl) * HW;
            const v4f v1a = *(const v4f*)(pa + po + s);   // L2-hot (same-XCD slab)
            const v4f v1b = *(const v4f*)(pb + po + s);
            v4f o2, o3;
            #pragma unroll
            for (int p = 0; p < 4; ++p) {
                const float sig = sigmoidf_(acc[p]);
                o2[p] = v1a[p] * sig;
                o3[p] = v1b[p] * sig;
            }
            __builtin_nontemporal_store(o2, (v4f*)(outb + (size_t)co2 * cS + po));
            __builtin_nontemporal_store(o3, (v4f*)(outb + (size_t)co3 * cS + po));
        }
    }
}

extern "C" void kernel_launch(void* const* d_in, const int* in_sizes, int n_in,
                              void* d_out, int out_size, void* d_ws, size_t ws_size,
                              hipStream_t stream) {
    const float* x     = (const float*)d_in[0];
    const float* cw    = (const float*)d_in[1];
    const float* cb    = (const float*)d_in[2];
    const float* wconv = (const float*)d_in[3];
    float* out = (float*)d_out;

    k_all<<<dim3(12288), 256, 0, stream>>>(x, cw, cb, wconv, out);
}